// Round 2
// baseline (610.232 us; speedup 1.0000x reference)
//
#include <hip/hip_runtime.h>
#include <hip/hip_bf16.h>
#include <math.h>

#define VOCAB 50257
#define DD 512
#define H 1024
#define SS 2048
#define LL 16
#define TWO_H 2048
#define XDIM 2576   // D + 2H + L
#define YDIM 1552   // H + L + D

// ws layout (fp32 offsets)
#define OFF_V      0        // 2048
#define OFF_CTX    2048     // 2048
#define OFF_RAW    4096     // 2048
#define OFF_SC     6144     // 2048
#define OFF_HF     8192     // 1024
#define OFF_XCAT   9216     // 2576
#define OFF_X1     11792    // 1024
#define OFF_X2     12816    // 1024
#define OFF_X3     13840    // 1024
#define OFF_GI     14864    // 3072
#define OFF_GH     17936    // 3072
#define OFF_Y      21008    // 1552
#define OFF_LOGITS 22560    // 50257
#define OFF_PMAX   72817    // 128
#define OFF_PSUM   72945    // 128
#define OFF_GMAX   73073    // 1
#define OFF_LOGZ   73074    // 1
#define OFF_FLAG   73075    // 1  (1.0 = inputs are bf16, 0.0 = inputs are fp32)

__device__ __forceinline__ float bf2f(unsigned short s) {
  union { unsigned u; float f; } t; t.u = ((unsigned)s) << 16; return t.f;
}
__device__ __forceinline__ float bflo(unsigned w) {
  union { unsigned u; float f; } t; t.u = w << 16; return t.f;
}
__device__ __forceinline__ float bfhi(unsigned w) {
  union { unsigned u; float f; } t; t.u = w & 0xffff0000u; return t.f;
}
__device__ __forceinline__ unsigned short f2bf(float f) {
  union { float f; unsigned u; } t; t.f = f;
  unsigned r = (t.u + 0x7FFFu + ((t.u >> 16) & 1u)) >> 16;
  return (unsigned short)r;
}

// dtype-dispatched scalar load / store
template<bool BF>
__device__ __forceinline__ float ldv(const void* p, size_t i) {
  if (BF) return bf2f(((const unsigned short*)p)[i]);
  else    return ((const float*)p)[i];
}
template<bool BF>
__device__ __forceinline__ void stv(void* p, size_t i, float v) {
  if (BF) ((unsigned short*)p)[i] = f2bf(v);
  else    ((float*)p)[i] = v;
}

// ---------- dtype detector ----------
// bf16 storage: even ushorts are real elements (|x| ~ 0.02, always < 1).
// fp32 storage: even ushorts are low mantissa bits -> random exponent as bf16.
__global__ void detect_kernel(const void* emb, float* flag) {
  if (threadIdx.x == 0) {
    const unsigned short* u = (const unsigned short*)emb;
    int ok = 1;
    for (int k = 0; k < 64; ++k) {
      float v = bf2f(u[2 * k]);
      if (!(fabsf(v) < 1.0f)) { ok = 0; break; }
    }
    flag[0] = ok ? 1.0f : 0.0f;
  }
}

__global__ __launch_bounds__(256) void zero_kernel(float* p, int n) {
  int i = blockIdx.x * 256 + threadIdx.x;
  if (i < n) p[i] = 0.f;
}

// ---------- v[k] = sum_j attn_W[j][k] * h[j] ----------
template<bool BF>
__device__ __forceinline__ void attn_v_body(const void* W, const void* hidden, float* v) {
  __shared__ float hs[64];
  int j0 = blockIdx.y * 64;
  if (threadIdx.x < 64) hs[threadIdx.x] = ldv<BF>(hidden, j0 + threadIdx.x);
  __syncthreads();
  int k = blockIdx.x * 256 + threadIdx.x;
  float acc = 0.f;
  #pragma unroll 8
  for (int j = 0; j < 64; ++j)
    acc += ldv<BF>(W, (size_t)(j0 + j) * TWO_H + k) * hs[j];
  atomicAdd(&v[k], acc);
}
__global__ __launch_bounds__(256)
void attn_v_kernel(const void* W, const void* hidden, float* v, const float* flag) {
  if (flag[0] > 0.5f) attn_v_body<true>(W, hidden, v);
  else                attn_v_body<false>(W, hidden, v);
}

// ---------- generic row-major matvec ----------
template<bool BF, bool RELU, bool BIAS>
__device__ __forceinline__ void matvec_body(const void* W, const void* bias,
                                            const float* x, float* out, int K) {
  int row = blockIdx.x;
  size_t base = (size_t)row * K;
  float acc = 0.f;
  for (int c = threadIdx.x; c < K; c += 128)
    acc += ldv<BF>(W, base + c) * x[c];
  __shared__ float red[128];
  red[threadIdx.x] = acc; __syncthreads();
  for (int s = 64; s > 0; s >>= 1) {
    if (threadIdx.x < s) red[threadIdx.x] += red[threadIdx.x + s];
    __syncthreads();
  }
  if (threadIdx.x == 0) {
    float r = red[0];
    if (BIAS) r += ldv<BF>(bias, row);
    if (RELU) r = fmaxf(r, 0.f);
    out[row] = r;
  }
}
template<bool RELU, bool BIAS>
__global__ __launch_bounds__(128)
void matvec_kernel(const void* W, const void* bias, const float* x,
                   float* out, int K, const float* flag) {
  if (flag[0] > 0.5f) matvec_body<true, RELU, BIAS>(W, bias, x, out, K);
  else                matvec_body<false, RELU, BIAS>(W, bias, x, out, K);
}

// ---------- softmax over 2048 raw scores ----------
template<bool BF>
__device__ __forceinline__ void softmax_body(const float* raw, float* scores, void* out_attn) {
  __shared__ float red[256];
  int t = threadIdx.x;
  float m = -3.4e38f;
  for (int i = t; i < SS; i += 256) m = fmaxf(m, raw[i]);
  red[t] = m; __syncthreads();
  for (int s = 128; s; s >>= 1) { if (t < s) red[t] = fmaxf(red[t], red[t + s]); __syncthreads(); }
  float gm = red[0]; __syncthreads();
  float sum = 0.f;
  for (int i = t; i < SS; i += 256) sum += expf(raw[i] - gm);
  red[t] = sum; __syncthreads();
  for (int s = 128; s; s >>= 1) { if (t < s) red[t] += red[t + s]; __syncthreads(); }
  float inv = 1.f / red[0];
  for (int i = t; i < SS; i += 256) {
    float sc = expf(raw[i] - gm) * inv;
    scores[i] = sc;
    stv<BF>(out_attn, (size_t)(VOCAB + H) + i, sc);
  }
}
__global__ __launch_bounds__(256)
void softmax2048_kernel(const float* raw, float* scores, void* d_out, const float* flag) {
  if (flag[0] > 0.5f) softmax_body<true>(raw, scores, d_out);
  else                softmax_body<false>(raw, scores, d_out);
}

// ---------- context[k] = sum_s scores[s] * enc[s][k] ----------
template<bool BF>
__device__ __forceinline__ void context_body(const void* enc, const float* scores, float* ctx) {
  __shared__ float ss[128];
  int s0 = blockIdx.y * 128;
  if (threadIdx.x < 128) ss[threadIdx.x] = scores[s0 + threadIdx.x];
  __syncthreads();
  int k = blockIdx.x * 256 + threadIdx.x;
  float acc = 0.f;
  #pragma unroll 4
  for (int s = 0; s < 128; ++s)
    acc += ss[s] * ldv<BF>(enc, (size_t)(s0 + s) * TWO_H + k);
  atomicAdd(&ctx[k], acc);
}
__global__ __launch_bounds__(256)
void context_kernel(const void* enc, const float* scores, float* ctx, const float* flag) {
  if (flag[0] > 0.5f) context_body<true>(enc, scores, ctx);
  else                context_body<false>(enc, scores, ctx);
}

// ---------- hf = fp32(hidden); xcat = [emb, ctx, nlg] ----------
template<bool BF>
__device__ __forceinline__ void build_xh_body(const void* hidden, const void* embedding,
                                              const void* nlg, const int* token,
                                              const float* ctx, float* hf, float* xcat) {
  int i = blockIdx.x * 256 + threadIdx.x;
  if (i < H) hf[i] = ldv<BF>(hidden, i);
  int j = i - H;
  if (j >= 0 && j < XDIM) {
    float val;
    if (j < DD) val = ldv<BF>(embedding, (size_t)token[0] * DD + j);
    else if (j < DD + TWO_H) val = ctx[j - DD];
    else val = ldv<BF>(nlg, j - DD - TWO_H);
    xcat[j] = val;
  }
}
__global__ __launch_bounds__(256)
void build_xh_kernel(const void* hidden, const void* embedding, const void* nlg,
                     const int* token, const float* ctx, float* hf, float* xcat,
                     const float* flag) {
  if (flag[0] > 0.5f) build_xh_body<true>(hidden, embedding, nlg, token, ctx, hf, xcat);
  else                build_xh_body<false>(hidden, embedding, nlg, token, ctx, hf, xcat);
}

// ---------- GRU gates + h_new + y = [h_new, nlg, emb] ----------
template<bool BF>
__device__ __forceinline__ void gru_body(const float* gi, const float* gh,
                                         const void* hidden, const void* nlg,
                                         const void* embedding, const int* token,
                                         float* y, void* d_out) {
  int i = blockIdx.x * 256 + threadIdx.x;
  if (i < H) {
    float r = 1.f / (1.f + expf(-(gi[i] + gh[i])));
    float z = 1.f / (1.f + expf(-(gi[H + i] + gh[H + i])));
    float n = tanhf(gi[2 * H + i] + r * gh[2 * H + i]);
    float hp = ldv<BF>(hidden, i);
    float hn = (1.f - z) * n + z * hp;
    y[i] = hn;
    stv<BF>(d_out, (size_t)VOCAB + i, hn);
  } else if (i < H + LL) {
    y[i] = ldv<BF>(nlg, i - H);
  } else if (i < YDIM) {
    y[i] = ldv<BF>(embedding, (size_t)token[0] * DD + (i - H - LL));
  }
}
__global__ __launch_bounds__(256)
void gru_gates_kernel(const float* gi, const float* gh, const void* hidden,
                      const void* nlg, const void* embedding, const int* token,
                      float* y, void* d_out, const float* flag) {
  if (flag[0] > 0.5f) gru_body<true>(gi, gh, hidden, nlg, embedding, token, y, d_out);
  else                gru_body<false>(gi, gh, hidden, nlg, embedding, token, y, d_out);
}

// ---------- logits: wave per row, vectorized 16B loads ----------
template<bool BF>
__device__ __forceinline__ void logits_body(const void* W, const void* bias,
                                            const float* y, float* logits) {
  __shared__ float ys[YDIM];
  for (int i = threadIdx.x; i < YDIM; i += 256) ys[i] = y[i];
  __syncthreads();
  int wave = threadIdx.x >> 6, lane = threadIdx.x & 63;
  int row = blockIdx.x * 4 + wave;
  if (row >= VOCAB) return;
  float acc = 0.f;
  if (BF) {
    const unsigned short* Wr = (const unsigned short*)W + (size_t)row * YDIM;
    for (int c = lane; c < (YDIM >> 3); c += 64) {   // 194 chunks of 8 bf16
      uint4 u = ((const uint4*)Wr)[c];
      const float* xp = ys + (c << 3);
      acc += bflo(u.x)*xp[0] + bfhi(u.x)*xp[1] + bflo(u.y)*xp[2] + bfhi(u.y)*xp[3]
           + bflo(u.z)*xp[4] + bfhi(u.z)*xp[5] + bflo(u.w)*xp[6] + bfhi(u.w)*xp[7];
    }
  } else {
    const float* Wr = (const float*)W + (size_t)row * YDIM;
    for (int c = lane; c < (YDIM >> 2); c += 64) {   // 388 chunks of 4 fp32
      float4 u = ((const float4*)Wr)[c];
      const float* xp = ys + (c << 2);
      acc += u.x*xp[0] + u.y*xp[1] + u.z*xp[2] + u.w*xp[3];
    }
  }
  #pragma unroll
  for (int off = 32; off; off >>= 1) acc += __shfl_down(acc, off, 64);
  if (lane == 0) logits[row] = acc + ldv<BF>(bias, row);
}
__global__ __launch_bounds__(256)
void logits_kernel(const void* W, const void* bias, const float* y,
                   float* logits, const float* flag) {
  if (flag[0] > 0.5f) logits_body<true>(W, bias, y, logits);
  else                logits_body<false>(W, bias, y, logits);
}

// ---------- log-softmax reductions ----------
__global__ __launch_bounds__(256)
void pmax_kernel(const float* logits, float* pmax) {
  float m = -3.4e38f;
  for (int i = blockIdx.x * 256 + threadIdx.x; i < VOCAB; i += gridDim.x * 256)
    m = fmaxf(m, logits[i]);
  __shared__ float red[256];
  red[threadIdx.x] = m; __syncthreads();
  for (int s = 128; s; s >>= 1) { if (threadIdx.x < s) red[threadIdx.x] = fmaxf(red[threadIdx.x], red[threadIdx.x + s]); __syncthreads(); }
  if (threadIdx.x == 0) pmax[blockIdx.x] = red[0];
}
__global__ __launch_bounds__(128)
void gmax_kernel(const float* pmax, float* gmax) {
  __shared__ float red[128];
  red[threadIdx.x] = pmax[threadIdx.x]; __syncthreads();
  for (int s = 64; s; s >>= 1) { if (threadIdx.x < s) red[threadIdx.x] = fmaxf(red[threadIdx.x], red[threadIdx.x + s]); __syncthreads(); }
  if (threadIdx.x == 0) gmax[0] = red[0];
}
__global__ __launch_bounds__(256)
void psum_kernel(const float* logits, const float* gmax, float* psum) {
  float gm = gmax[0];
  float s = 0.f;
  for (int i = blockIdx.x * 256 + threadIdx.x; i < VOCAB; i += gridDim.x * 256)
    s += expf(logits[i] - gm);
  __shared__ float red[256];
  red[threadIdx.x] = s; __syncthreads();
  for (int t = 128; t; t >>= 1) { if (threadIdx.x < t) red[threadIdx.x] += red[threadIdx.x + t]; __syncthreads(); }
  if (threadIdx.x == 0) psum[blockIdx.x] = red[0];
}
__global__ __launch_bounds__(128)
void logz_kernel(const float* psum, const float* gmax, float* logz) {
  __shared__ float red[128];
  red[threadIdx.x] = psum[threadIdx.x]; __syncthreads();
  for (int s = 64; s; s >>= 1) { if (threadIdx.x < s) red[threadIdx.x] += red[threadIdx.x + s]; __syncthreads(); }
  if (threadIdx.x == 0) logz[0] = gmax[0] + logf(red[0]);
}

template<bool BF>
__device__ __forceinline__ void writeout_body(const float* logits, const float* logz, void* out) {
  int i = blockIdx.x * 256 + threadIdx.x;
  if (i < VOCAB) stv<BF>(out, i, logits[i] - logz[0]);
}
__global__ __launch_bounds__(256)
void writeout_kernel(const float* logits, const float* logz, void* out, const float* flag) {
  if (flag[0] > 0.5f) writeout_body<true>(logits, logz, out);
  else                writeout_body<false>(logits, logz, out);
}

extern "C" void kernel_launch(void* const* d_in, const int* in_sizes, int n_in,
                              void* d_out, int out_size, void* d_ws, size_t ws_size,
                              hipStream_t stream) {
  (void)in_sizes; (void)n_in; (void)out_size; (void)ws_size;
  const int* token      = (const int*)d_in[0];
  const void* hidden    = d_in[1];
  const void* enc       = d_in[2];
  const void* nlg       = d_in[3];
  const void* embedding = d_in[4];
  const void* attn_W    = d_in[5];
  // d_in[6] = attn_b: (attn_b . h) is constant across s => cancels in softmax
  const void* comb_W    = d_in[7];
  const void* comb_b    = d_in[8];
  const void* fc1_W     = d_in[9];
  const void* fc1_b     = d_in[10];
  const void* fc2_W     = d_in[11];
  const void* fc2_b     = d_in[12];
  const void* gru_Wih   = d_in[13];
  const void* gru_Whh   = d_in[14];
  const void* gru_bih   = d_in[15];
  const void* gru_bhh   = d_in[16];
  const void* out_W     = d_in[17];
  const void* out_b     = d_in[18];

  float* ws = (float*)d_ws;
  float* flag = ws + OFF_FLAG;

  detect_kernel<<<1, 64, 0, stream>>>(embedding, flag);
  zero_kernel<<<16, 256, 0, stream>>>(ws, 4096);  // v + ctx accumulators
  attn_v_kernel<<<dim3(8, 16), 256, 0, stream>>>(attn_W, hidden, ws + OFF_V, flag);
  matvec_kernel<false, false><<<SS, 128, 0, stream>>>(enc, nullptr, ws + OFF_V, ws + OFF_RAW, TWO_H, flag);
  softmax2048_kernel<<<1, 256, 0, stream>>>(ws + OFF_RAW, ws + OFF_SC, d_out, flag);
  context_kernel<<<dim3(8, 16), 256, 0, stream>>>(enc, ws + OFF_SC, ws + OFF_CTX, flag);
  build_xh_kernel<<<15, 256, 0, stream>>>(hidden, embedding, nlg, token, ws + OFF_CTX,
                                          ws + OFF_HF, ws + OFF_XCAT, flag);
  matvec_kernel<true, true><<<H, 128, 0, stream>>>(comb_W, comb_b, ws + OFF_XCAT, ws + OFF_X1, XDIM, flag);
  matvec_kernel<true, true><<<H, 128, 0, stream>>>(fc1_W, fc1_b, ws + OFF_X1, ws + OFF_X2, H, flag);
  matvec_kernel<true, true><<<H, 128, 0, stream>>>(fc2_W, fc2_b, ws + OFF_X2, ws + OFF_X3, H, flag);
  matvec_kernel<false, true><<<3 * H, 128, 0, stream>>>(gru_Wih, gru_bih, ws + OFF_X3, ws + OFF_GI, H, flag);
  matvec_kernel<false, true><<<3 * H, 128, 0, stream>>>(gru_Whh, gru_bhh, ws + OFF_HF, ws + OFF_GH, H, flag);
  gru_gates_kernel<<<7, 256, 0, stream>>>(ws + OFF_GI, ws + OFF_GH, hidden, nlg, embedding, token,
                                          ws + OFF_Y, d_out, flag);
  logits_kernel<<<(VOCAB + 3) / 4, 256, 0, stream>>>(out_W, out_b, ws + OFF_Y, ws + OFF_LOGITS, flag);
  pmax_kernel<<<128, 256, 0, stream>>>(ws + OFF_LOGITS, ws + OFF_PMAX);
  gmax_kernel<<<1, 128, 0, stream>>>(ws + OFF_PMAX, ws + OFF_GMAX);
  psum_kernel<<<128, 256, 0, stream>>>(ws + OFF_LOGITS, ws + OFF_GMAX, ws + OFF_PSUM);
  logz_kernel<<<1, 128, 0, stream>>>(ws + OFF_PSUM, ws + OFF_GMAX, ws + OFF_LOGZ);
  writeout_kernel<<<(VOCAB + 255) / 256, 256, 0, stream>>>(ws + OFF_LOGITS, ws + OFF_LOGZ, d_out, flag);
}